// Round 3
// baseline (1377.098 us; speedup 1.0000x reference)
//
#include <hip/hip_runtime.h>

#define BATCH 32
#define NPTS 131072           // 2^17
#define LOGN 17
#define RES 24
#define R3 (RES*RES*RES)      // 13824
#define NBLK_PER_B 16
#define CHUNK (NPTS/NBLK_PER_B)  // 8192

// ws layout (bytes):
//   [0,     12288)  double partial[512][3]      (per-block coord sums)
//   [12288, 13056)  double mean[32][3]          (final per-batch mean)
//   [13056, 13312)  ull    maxsq[32]            (max squared dist, double bits)
//   [16384, ... )   float  accum[32*13824][4]   (cnt, f1sum, f2sum, f3sum)
#define WS_PARTIAL 0
#define WS_MEAN    12288
#define WS_MAXSQ   13056
#define WS_ACCUM   16384
#define ACCUM_BYTES ((size_t)BATCH * R3 * 4 * sizeof(float))

__global__ __launch_bounds__(256) void k_mean(const float* __restrict__ pts,
                                              double* __restrict__ partial) {
    int blk = blockIdx.x;
    int b = blk >> 4, c = blk & 15;
    const float2* base = (const float2*)pts + ((size_t)b * NPTS + (size_t)c * CHUNK) * 3;
    double s0 = 0, s1 = 0, s2 = 0;
    for (int i = threadIdx.x; i < CHUNK; i += 256) {
        float2 a = base[(size_t)i * 3];
        float2 d = base[(size_t)i * 3 + 1];
        s0 += (double)a.x; s1 += (double)a.y; s2 += (double)d.x;
    }
    for (int off = 32; off; off >>= 1) {
        s0 += __shfl_down(s0, off);
        s1 += __shfl_down(s1, off);
        s2 += __shfl_down(s2, off);
    }
    __shared__ double sh[4][3];
    int lane = threadIdx.x & 63, w = threadIdx.x >> 6;
    if (lane == 0) { sh[w][0] = s0; sh[w][1] = s1; sh[w][2] = s2; }
    __syncthreads();
    if (threadIdx.x == 0) {
        double t0 = 0, t1 = 0, t2 = 0;
        for (int q = 0; q < 4; q++) { t0 += sh[q][0]; t1 += sh[q][1]; t2 += sh[q][2]; }
        partial[(size_t)blk * 3 + 0] = t0;
        partial[(size_t)blk * 3 + 1] = t1;
        partial[(size_t)blk * 3 + 2] = t2;
    }
}

__global__ __launch_bounds__(64) void k_meanred(const double* __restrict__ partial,
                                                double* __restrict__ mean) {
    int b = threadIdx.x;
    if (b >= BATCH) return;
    double t0 = 0, t1 = 0, t2 = 0;
    for (int c = 0; c < NBLK_PER_B; c++) {
        const double* p = partial + ((size_t)b * NBLK_PER_B + c) * 3;
        t0 += p[0]; t1 += p[1]; t2 += p[2];
    }
    mean[b * 3 + 0] = t0 / (double)NPTS;
    mean[b * 3 + 1] = t1 / (double)NPTS;
    mean[b * 3 + 2] = t2 / (double)NPTS;
}

__global__ __launch_bounds__(256) void k_max(const float* __restrict__ pts,
                                             const double* __restrict__ mean,
                                             unsigned long long* __restrict__ maxsq) {
    int blk = blockIdx.x;
    int b = blk >> 4, c = blk & 15;
    double mx = mean[b * 3], my = mean[b * 3 + 1], mz = mean[b * 3 + 2];
    const float2* base = (const float2*)pts + ((size_t)b * NPTS + (size_t)c * CHUNK) * 3;
    double m = 0.0;
    for (int i = threadIdx.x; i < CHUNK; i += 256) {
        float2 a = base[(size_t)i * 3];
        float2 d = base[(size_t)i * 3 + 1];
        double dx = (double)a.x - mx;
        double dy = (double)a.y - my;
        double dz = (double)d.x - mz;
        double s = dx * dx + dy * dy + dz * dz;
        m = fmax(m, s);
    }
    for (int off = 32; off; off >>= 1)
        m = fmax(m, __shfl_down(m, off));
    __shared__ double sh[4];
    int lane = threadIdx.x & 63, w = threadIdx.x >> 6;
    if (lane == 0) sh[w] = m;
    __syncthreads();
    if (threadIdx.x == 0) {
        double t = fmax(fmax(sh[0], sh[1]), fmax(sh[2], sh[3]));
        atomicMax(&maxsq[b], (unsigned long long)__double_as_longlong(t));
    }
}

__global__ __launch_bounds__(256) void k_scatter(const float* __restrict__ pts,
                                                 const double* __restrict__ mean,
                                                 const unsigned long long* __restrict__ maxsq,
                                                 float* __restrict__ accum) {
    int gid = blockIdx.x * 256 + threadIdx.x;   // < BATCH*NPTS
    int b = gid >> LOGN;
    double mx = mean[b * 3], my = mean[b * 3 + 1], mz = mean[b * 3 + 2];
    double denom = 2.0 * sqrt(__longlong_as_double((long long)maxsq[b]));
    const float2* p = (const float2*)pts + (size_t)gid * 3;
    float2 a = p[0], d = p[1], e = p[2];
    // reference (np-f64 path): nc = (c-mean)/denom + 0.5; v = clip(nc*24,0,23); round RTE
    double vx = ((double)a.x - mx) / denom + 0.5;
    double vy = ((double)a.y - my) / denom + 0.5;
    double vz = ((double)d.x - mz) / denom + 0.5;
    vx = fmin(fmax(vx * (double)RES, 0.0), (double)(RES - 1));
    vy = fmin(fmax(vy * (double)RES, 0.0), (double)(RES - 1));
    vz = fmin(fmax(vz * (double)RES, 0.0), (double)(RES - 1));
    int qx = (int)rint(vx);
    int qy = (int)rint(vy);
    int qz = (int)rint(vz);
    int cell = b * R3 + qx * (RES * RES) + qy * RES + qz;
    float* acc = accum + (size_t)cell * 4;
    atomicAdd(acc + 0, 1.0f);
    atomicAdd(acc + 1, d.y);
    atomicAdd(acc + 2, e.x);
    atomicAdd(acc + 3, e.y);
}

__global__ __launch_bounds__(256) void k_final(const float* __restrict__ accum,
                                               float* __restrict__ out) {
    int cell = blockIdx.x * 256 + threadIdx.x;  // < BATCH*R3 (exact multiple)
    const float4 a = ((const float4*)accum)[cell];
    float cnt = a.x;
    int b = cell / R3;
    int r = cell - b * R3;
    size_t obase = (size_t)b * 4 * R3 + r;
    if (cnt > 0.0f) {
        out[obase]            = 1.0f;
        out[obase + R3]       = a.y / cnt;
        out[obase + 2 * R3]   = a.z / cnt;
        out[obase + 3 * R3]   = a.w / cnt;
    } else {
        out[obase]            = 0.0f;
        out[obase + R3]       = 0.0f;
        out[obase + 2 * R3]   = 0.0f;
        out[obase + 3 * R3]   = 0.0f;
    }
}

extern "C" void kernel_launch(void* const* d_in, const int* in_sizes, int n_in,
                              void* d_out, int out_size, void* d_ws, size_t ws_size,
                              hipStream_t stream) {
    const float* pts = (const float*)d_in[0];
    float* out = (float*)d_out;
    char* ws = (char*)d_ws;
    double* partial = (double*)(ws + WS_PARTIAL);
    double* mean = (double*)(ws + WS_MEAN);
    unsigned long long* maxsq = (unsigned long long*)(ws + WS_MAXSQ);
    float* accum = (float*)(ws + WS_ACCUM);

    // zero maxsq + accum (partial/mean are fully overwritten each call)
    hipMemsetAsync(ws + WS_MAXSQ, 0, (WS_ACCUM - WS_MAXSQ) + ACCUM_BYTES, stream);

    k_mean<<<BATCH * NBLK_PER_B, 256, 0, stream>>>(pts, partial);
    k_meanred<<<1, 64, 0, stream>>>(partial, mean);
    k_max<<<BATCH * NBLK_PER_B, 256, 0, stream>>>(pts, mean, maxsq);
    k_scatter<<<(BATCH * NPTS) / 256, 256, 0, stream>>>(pts, mean, maxsq, accum);
    k_final<<<(BATCH * R3) / 256, 256, 0, stream>>>(accum, out);
}

// Round 4
// 435.902 us; speedup vs baseline: 3.1592x; 3.1592x over previous
//
#include <hip/hip_runtime.h>

#define BATCH 32
#define NPTS 131072           // 2^17
#define RES 24
#define R3 (RES*RES*RES)      // 13824
#define NPART 4               // qx partitions
#define PCELLS (R3/NPART)     // 3456 cells per partition (qx-contiguous)
#define NBLK_PER_B 16
#define CHUNK (NPTS/NBLK_PER_B)  // 8192

// ws layout (bytes):
//   [0,     12288)  double partial[512][3]      (per-block coord sums)
//   [12288, 13056)  double mean[32][3]          (final per-batch mean)
//   [13056, 13312)  ull    maxsq[32]            (max squared dist, double bits)
#define WS_PARTIAL 0
#define WS_MEAN    12288
#define WS_MAXSQ   13056

__global__ __launch_bounds__(256) void k_mean(const float* __restrict__ pts,
                                              double* __restrict__ partial) {
    int blk = blockIdx.x;
    int b = blk >> 4, c = blk & 15;
    const float2* base = (const float2*)pts + ((size_t)b * NPTS + (size_t)c * CHUNK) * 3;
    double s0 = 0, s1 = 0, s2 = 0;
    for (int i = threadIdx.x; i < CHUNK; i += 256) {
        float2 a = base[(size_t)i * 3];
        float2 d = base[(size_t)i * 3 + 1];
        s0 += (double)a.x; s1 += (double)a.y; s2 += (double)d.x;
    }
    for (int off = 32; off; off >>= 1) {
        s0 += __shfl_down(s0, off);
        s1 += __shfl_down(s1, off);
        s2 += __shfl_down(s2, off);
    }
    __shared__ double sh[4][3];
    int lane = threadIdx.x & 63, w = threadIdx.x >> 6;
    if (lane == 0) { sh[w][0] = s0; sh[w][1] = s1; sh[w][2] = s2; }
    __syncthreads();
    if (threadIdx.x == 0) {
        double t0 = 0, t1 = 0, t2 = 0;
        for (int q = 0; q < 4; q++) { t0 += sh[q][0]; t1 += sh[q][1]; t2 += sh[q][2]; }
        partial[(size_t)blk * 3 + 0] = t0;
        partial[(size_t)blk * 3 + 1] = t1;
        partial[(size_t)blk * 3 + 2] = t2;
    }
}

__global__ __launch_bounds__(64) void k_meanred(const double* __restrict__ partial,
                                                double* __restrict__ mean) {
    int b = threadIdx.x;
    if (b >= BATCH) return;
    double t0 = 0, t1 = 0, t2 = 0;
    for (int c = 0; c < NBLK_PER_B; c++) {
        const double* p = partial + ((size_t)b * NBLK_PER_B + c) * 3;
        t0 += p[0]; t1 += p[1]; t2 += p[2];
    }
    mean[b * 3 + 0] = t0 / (double)NPTS;
    mean[b * 3 + 1] = t1 / (double)NPTS;
    mean[b * 3 + 2] = t2 / (double)NPTS;
}

__global__ __launch_bounds__(256) void k_max(const float* __restrict__ pts,
                                             const double* __restrict__ mean,
                                             unsigned long long* __restrict__ maxsq) {
    int blk = blockIdx.x;
    int b = blk >> 4, c = blk & 15;
    double mx = mean[b * 3], my = mean[b * 3 + 1], mz = mean[b * 3 + 2];
    const float2* base = (const float2*)pts + ((size_t)b * NPTS + (size_t)c * CHUNK) * 3;
    double m = 0.0;
    for (int i = threadIdx.x; i < CHUNK; i += 256) {
        float2 a = base[(size_t)i * 3];
        float2 d = base[(size_t)i * 3 + 1];
        double dx = (double)a.x - mx;
        double dy = (double)a.y - my;
        double dz = (double)d.x - mz;
        double s = dx * dx + dy * dy + dz * dz;
        m = fmax(m, s);
    }
    for (int off = 32; off; off >>= 1)
        m = fmax(m, __shfl_down(m, off));
    __shared__ double sh[4];
    int lane = threadIdx.x & 63, w = threadIdx.x >> 6;
    if (lane == 0) sh[w] = m;
    __syncthreads();
    if (threadIdx.x == 0) {
        double t = fmax(fmax(sh[0], sh[1]), fmax(sh[2], sh[3]));
        atomicMax(&maxsq[b], (unsigned long long)__double_as_longlong(t));
    }
}

// One block per (batch, qx-partition). Stream the whole batch, accumulate the
// partition's cells in LDS (f32 LDS atomics — no global atomics anywhere),
// then write averaged output directly. LDS image: 3456 cells x 4 f32 = 55296 B.
__global__ __launch_bounds__(512) void k_scatter_fused(const float* __restrict__ pts,
                                                       const double* __restrict__ mean,
                                                       const unsigned long long* __restrict__ maxsq,
                                                       float* __restrict__ out) {
    __shared__ float acc[PCELLS][4];
    int b = blockIdx.x >> 2;        // batch
    int p = blockIdx.x & 3;         // qx partition: qx in [6p, 6p+6)
    for (int c = threadIdx.x; c < PCELLS * 4; c += 512)
        ((float*)acc)[c] = 0.0f;
    __syncthreads();

    double mx = mean[b * 3], my = mean[b * 3 + 1], mz = mean[b * 3 + 2];
    double denom = 2.0 * sqrt(__longlong_as_double((long long)maxsq[b]));
    const float2* base = (const float2*)pts + (size_t)b * NPTS * 3;

    for (int i = threadIdx.x; i < NPTS; i += 512) {
        float2 a = base[(size_t)i * 3];
        float2 d = base[(size_t)i * 3 + 1];
        float2 e = base[(size_t)i * 3 + 2];
        // identical f64 transform as the passing round (np-f64 path, RTE)
        double vx = ((double)a.x - mx) / denom + 0.5;
        double vy = ((double)a.y - my) / denom + 0.5;
        double vz = ((double)d.x - mz) / denom + 0.5;
        vx = fmin(fmax(vx * (double)RES, 0.0), (double)(RES - 1));
        vy = fmin(fmax(vy * (double)RES, 0.0), (double)(RES - 1));
        vz = fmin(fmax(vz * (double)RES, 0.0), (double)(RES - 1));
        int qx = (int)rint(vx);
        int qy = (int)rint(vy);
        int qz = (int)rint(vz);
        if ((qx / 6) == p) {
            int lidx = (qx - p * 6) * (RES * RES) + qy * RES + qz;
            atomicAdd(&acc[lidx][0], 1.0f);
            atomicAdd(&acc[lidx][1], d.y);
            atomicAdd(&acc[lidx][2], e.x);
            atomicAdd(&acc[lidx][3], e.y);
        }
    }
    __syncthreads();

    // partition cells are qx-contiguous: global flat cell r = p*PCELLS + c
    size_t obase = (size_t)b * 4 * R3;
    for (int c = threadIdx.x; c < PCELLS; c += 512) {
        float cnt = acc[c][0];
        float f1 = acc[c][1], f2 = acc[c][2], f3 = acc[c][3];
        size_t r = obase + (size_t)(p * PCELLS + c);
        if (cnt > 0.0f) {
            out[r]            = 1.0f;
            out[r + R3]       = f1 / cnt;
            out[r + 2 * R3]   = f2 / cnt;
            out[r + 3 * R3]   = f3 / cnt;
        } else {
            out[r]            = 0.0f;
            out[r + R3]       = 0.0f;
            out[r + 2 * R3]   = 0.0f;
            out[r + 3 * R3]   = 0.0f;
        }
    }
}

extern "C" void kernel_launch(void* const* d_in, const int* in_sizes, int n_in,
                              void* d_out, int out_size, void* d_ws, size_t ws_size,
                              hipStream_t stream) {
    const float* pts = (const float*)d_in[0];
    float* out = (float*)d_out;
    char* ws = (char*)d_ws;
    double* partial = (double*)(ws + WS_PARTIAL);
    double* mean = (double*)(ws + WS_MEAN);
    unsigned long long* maxsq = (unsigned long long*)(ws + WS_MAXSQ);

    hipMemsetAsync(ws + WS_MAXSQ, 0, BATCH * sizeof(unsigned long long), stream);

    k_mean<<<BATCH * NBLK_PER_B, 256, 0, stream>>>(pts, partial);
    k_meanred<<<1, 64, 0, stream>>>(partial, mean);
    k_max<<<BATCH * NBLK_PER_B, 256, 0, stream>>>(pts, mean, maxsq);
    k_scatter_fused<<<BATCH * NPART, 512, 0, stream>>>(pts, mean, maxsq, out);
}

// Round 5
// 356.073 us; speedup vs baseline: 3.8675x; 1.2242x over previous
//
#include <hip/hip_runtime.h>

#define BATCH 32
#define NPTS 131072           // 2^17 points per cloud
#define RES 24
#define R3 (RES*RES*RES)      // 13824
#define NPART 8               // qx slabs of 3
#define SLAB 3
#define PCELLS (SLAB*RES*RES) // 1728 cells -> 27648 B LDS
#define NBLK_PER_B 16
#define CHUNK (NPTS/NBLK_PER_B)  // 8192

// ws layout (bytes):
//   [0,     12288)  double partial[512][3]
//   [12288, 13056)  double mean[32][3]
//   [13056, 13312)  ull    maxsq[32]
#define WS_PARTIAL 0
#define WS_MEAN    12288
#define WS_MAXSQ   13056

__global__ __launch_bounds__(256) void k_mean(const float* __restrict__ pts,
                                              double* __restrict__ partial) {
    int blk = blockIdx.x;
    int b = blk >> 4, c = blk & 15;
    const float4* base = (const float4*)(pts + ((size_t)b * NPTS + (size_t)c * CHUNK) * 6);
    double s0 = 0, s1 = 0, s2 = 0;
    for (int i = threadIdx.x; i < CHUNK / 2; i += 256) {
        float4 v0 = base[(size_t)i * 3];
        float4 v1 = base[(size_t)i * 3 + 1];
        float4 v2 = base[(size_t)i * 3 + 2];
        s0 += (double)v0.x + (double)v1.z;
        s1 += (double)v0.y + (double)v1.w;
        s2 += (double)v0.z + (double)v2.x;
    }
    for (int off = 32; off; off >>= 1) {
        s0 += __shfl_down(s0, off);
        s1 += __shfl_down(s1, off);
        s2 += __shfl_down(s2, off);
    }
    __shared__ double sh[4][3];
    int lane = threadIdx.x & 63, w = threadIdx.x >> 6;
    if (lane == 0) { sh[w][0] = s0; sh[w][1] = s1; sh[w][2] = s2; }
    __syncthreads();
    if (threadIdx.x == 0) {
        double t0 = 0, t1 = 0, t2 = 0;
        for (int q = 0; q < 4; q++) { t0 += sh[q][0]; t1 += sh[q][1]; t2 += sh[q][2]; }
        partial[(size_t)blk * 3 + 0] = t0;
        partial[(size_t)blk * 3 + 1] = t1;
        partial[(size_t)blk * 3 + 2] = t2;
    }
}

__global__ __launch_bounds__(64) void k_meanred(const double* __restrict__ partial,
                                                double* __restrict__ mean) {
    int b = threadIdx.x;
    if (b >= BATCH) return;
    double t0 = 0, t1 = 0, t2 = 0;
    for (int c = 0; c < NBLK_PER_B; c++) {
        const double* p = partial + ((size_t)b * NBLK_PER_B + c) * 3;
        t0 += p[0]; t1 += p[1]; t2 += p[2];
    }
    mean[b * 3 + 0] = t0 / (double)NPTS;
    mean[b * 3 + 1] = t1 / (double)NPTS;
    mean[b * 3 + 2] = t2 / (double)NPTS;
}

__global__ __launch_bounds__(256) void k_max(const float* __restrict__ pts,
                                             const double* __restrict__ mean,
                                             unsigned long long* __restrict__ maxsq) {
    int blk = blockIdx.x;
    int b = blk >> 4, c = blk & 15;
    double mx = mean[b * 3], my = mean[b * 3 + 1], mz = mean[b * 3 + 2];
    const float4* base = (const float4*)(pts + ((size_t)b * NPTS + (size_t)c * CHUNK) * 6);
    double m = 0.0;
    for (int i = threadIdx.x; i < CHUNK / 2; i += 256) {
        float4 v0 = base[(size_t)i * 3];
        float4 v1 = base[(size_t)i * 3 + 1];
        float4 v2 = base[(size_t)i * 3 + 2];
        double dx = (double)v0.x - mx, dy = (double)v0.y - my, dz = (double)v0.z - mz;
        m = fmax(m, dx * dx + dy * dy + dz * dz);
        dx = (double)v1.z - mx; dy = (double)v1.w - my; dz = (double)v2.x - mz;
        m = fmax(m, dx * dx + dy * dy + dz * dz);
    }
    for (int off = 32; off; off >>= 1)
        m = fmax(m, __shfl_down(m, off));
    __shared__ double sh[4];
    int lane = threadIdx.x & 63, w = threadIdx.x >> 6;
    if (lane == 0) sh[w] = m;
    __syncthreads();
    if (threadIdx.x == 0) {
        double t = fmax(fmax(sh[0], sh[1]), fmax(sh[2], sh[3]));
        atomicMax(&maxsq[b], (unsigned long long)__double_as_longlong(t));
    }
}

// One block per (batch, qx-slab). 1024 threads stream the whole batch (2 points
// = 3 float4 per thread-iter), pre-filter on an f32 x-range (guard-banded; the
// exact f64 path still decides membership), accumulate in LDS, write averaged
// output directly. No global atomics.
__global__ __launch_bounds__(1024, 4) void k_scatter_fused(const float* __restrict__ pts,
                                                           const double* __restrict__ mean,
                                                           const unsigned long long* __restrict__ maxsq,
                                                           float* __restrict__ out) {
    __shared__ float acc[PCELLS][4];
    int b = blockIdx.x >> 3;
    int p = blockIdx.x & 7;
    for (int c = threadIdx.x; c < PCELLS * 4; c += 1024)
        ((float*)acc)[c] = 0.0f;
    __syncthreads();

    double mx = mean[b * 3], my = mean[b * 3 + 1], mz = mean[b * 3 + 2];
    double denom = 2.0 * sqrt(__longlong_as_double((long long)maxsq[b]));
    // slab x-range: qx >= 3p  <=>  vx*24 >= 3p-0.5 ; qx <= 3p+2 <=> vx*24 <= 3p+2.5
    double xlo = mx + denom * (((double)(3 * p) - 0.5) / 24.0 - 0.5);
    double xhi = mx + denom * (((double)(3 * p) + 2.5) / 24.0 - 0.5);
    float flo = (p == 0)         ? -3.0e38f : (float)(xlo - 1e-4);
    float fhi = (p == NPART - 1) ?  3.0e38f : (float)(xhi + 1e-4);

    const float4* base = (const float4*)(pts + (size_t)b * NPTS * 6);
    for (int i = threadIdx.x; i < NPTS / 2; i += 1024) {
        float4 v0 = base[(size_t)i * 3];
        float4 v1 = base[(size_t)i * 3 + 1];
        float4 v2 = base[(size_t)i * 3 + 2];
        // point A: xyz = v0.xyz, feats = v0.w, v1.x, v1.y
        {
            float x = v0.x;
            if (x >= flo && x <= fhi) {
                double vx = ((double)x - mx) / denom + 0.5;
                vx = fmin(fmax(vx * 24.0, 0.0), 23.0);
                int qx = (int)rint(vx);
                if (qx >= 3 * p && qx < 3 * p + 3) {
                    double vy = ((double)v0.y - my) / denom + 0.5;
                    double vz = ((double)v0.z - mz) / denom + 0.5;
                    vy = fmin(fmax(vy * 24.0, 0.0), 23.0);
                    vz = fmin(fmax(vz * 24.0, 0.0), 23.0);
                    int qy = (int)rint(vy);
                    int qz = (int)rint(vz);
                    int l = (qx - 3 * p) * (RES * RES) + qy * RES + qz;
                    atomicAdd(&acc[l][0], 1.0f);
                    atomicAdd(&acc[l][1], v0.w);
                    atomicAdd(&acc[l][2], v1.x);
                    atomicAdd(&acc[l][3], v1.y);
                }
            }
        }
        // point B: xyz = v1.z, v1.w, v2.x, feats = v2.y, v2.z, v2.w
        {
            float x = v1.z;
            if (x >= flo && x <= fhi) {
                double vx = ((double)x - mx) / denom + 0.5;
                vx = fmin(fmax(vx * 24.0, 0.0), 23.0);
                int qx = (int)rint(vx);
                if (qx >= 3 * p && qx < 3 * p + 3) {
                    double vy = ((double)v1.w - my) / denom + 0.5;
                    double vz = ((double)v2.x - mz) / denom + 0.5;
                    vy = fmin(fmax(vy * 24.0, 0.0), 23.0);
                    vz = fmin(fmax(vz * 24.0, 0.0), 23.0);
                    int qy = (int)rint(vy);
                    int qz = (int)rint(vz);
                    int l = (qx - 3 * p) * (RES * RES) + qy * RES + qz;
                    atomicAdd(&acc[l][0], 1.0f);
                    atomicAdd(&acc[l][1], v2.y);
                    atomicAdd(&acc[l][2], v2.z);
                    atomicAdd(&acc[l][3], v2.w);
                }
            }
        }
    }
    __syncthreads();

    // slab cells are qx-contiguous: global flat cell = p*PCELLS + c
    size_t obase = (size_t)b * 4 * R3 + (size_t)p * PCELLS;
    for (int c = threadIdx.x; c < PCELLS; c += 1024) {
        float cnt = acc[c][0];
        size_t r = obase + c;
        if (cnt > 0.0f) {
            out[r]          = 1.0f;
            out[r + R3]     = acc[c][1] / cnt;
            out[r + 2 * R3] = acc[c][2] / cnt;
            out[r + 3 * R3] = acc[c][3] / cnt;
        } else {
            out[r]          = 0.0f;
            out[r + R3]     = 0.0f;
            out[r + 2 * R3] = 0.0f;
            out[r + 3 * R3] = 0.0f;
        }
    }
}

extern "C" void kernel_launch(void* const* d_in, const int* in_sizes, int n_in,
                              void* d_out, int out_size, void* d_ws, size_t ws_size,
                              hipStream_t stream) {
    const float* pts = (const float*)d_in[0];
    float* out = (float*)d_out;
    char* ws = (char*)d_ws;
    double* partial = (double*)(ws + WS_PARTIAL);
    double* mean = (double*)(ws + WS_MEAN);
    unsigned long long* maxsq = (unsigned long long*)(ws + WS_MAXSQ);

    hipMemsetAsync(ws + WS_MAXSQ, 0, BATCH * sizeof(unsigned long long), stream);

    k_mean<<<BATCH * NBLK_PER_B, 256, 0, stream>>>(pts, partial);
    k_meanred<<<1, 64, 0, stream>>>(partial, mean);
    k_max<<<BATCH * NBLK_PER_B, 256, 0, stream>>>(pts, mean, maxsq);
    k_scatter_fused<<<BATCH * NPART, 1024, 0, stream>>>(pts, mean, maxsq, out);
}

// Round 6
// 247.194 us; speedup vs baseline: 5.5709x; 1.4405x over previous
//
#include <hip/hip_runtime.h>

#define BATCH 32
#define NPTS 131072           // 2^17 points per cloud
#define RES 24
#define R3 (RES*RES*RES)      // 13824
#define NPART 4               // qx slabs of 6
#define SLAB 6
#define PCELLS (SLAB*RES*RES) // 3456 cells -> 55296 B LDS
#define NCHUNK 4
#define CPTS (NPTS/NCHUNK)    // 32768 points per chunk
#define NBLK_PER_B 16
#define CHUNK (NPTS/NBLK_PER_B)  // 8192 (mean/max kernels)

// ws layout (bytes):
//   [0,     12288)  double partial[512][3]
//   [12288, 13056)  double mean[32][3]
//   [13056, 13312)  ull    maxsq[32]
//   [16384, ...  )  float  accum[32*13824][4]
#define WS_PARTIAL 0
#define WS_MEAN    12288
#define WS_MAXSQ   13056
#define WS_ACCUM   16384
#define ACCUM_BYTES ((size_t)BATCH * R3 * 4 * sizeof(float))

__global__ __launch_bounds__(256) void k_mean(const float* __restrict__ pts,
                                              double* __restrict__ partial) {
    int blk = blockIdx.x;
    int b = blk >> 4, c = blk & 15;
    const float4* base = (const float4*)(pts + ((size_t)b * NPTS + (size_t)c * CHUNK) * 6);
    double s0 = 0, s1 = 0, s2 = 0;
    for (int i = threadIdx.x; i < CHUNK / 2; i += 256) {
        float4 v0 = base[(size_t)i * 3];
        float4 v1 = base[(size_t)i * 3 + 1];
        float4 v2 = base[(size_t)i * 3 + 2];
        s0 += (double)v0.x + (double)v1.z;
        s1 += (double)v0.y + (double)v1.w;
        s2 += (double)v0.z + (double)v2.x;
    }
    for (int off = 32; off; off >>= 1) {
        s0 += __shfl_down(s0, off);
        s1 += __shfl_down(s1, off);
        s2 += __shfl_down(s2, off);
    }
    __shared__ double sh[4][3];
    int lane = threadIdx.x & 63, w = threadIdx.x >> 6;
    if (lane == 0) { sh[w][0] = s0; sh[w][1] = s1; sh[w][2] = s2; }
    __syncthreads();
    if (threadIdx.x == 0) {
        double t0 = 0, t1 = 0, t2 = 0;
        for (int q = 0; q < 4; q++) { t0 += sh[q][0]; t1 += sh[q][1]; t2 += sh[q][2]; }
        partial[(size_t)blk * 3 + 0] = t0;
        partial[(size_t)blk * 3 + 1] = t1;
        partial[(size_t)blk * 3 + 2] = t2;
    }
}

__global__ __launch_bounds__(64) void k_meanred(const double* __restrict__ partial,
                                                double* __restrict__ mean) {
    int b = threadIdx.x;
    if (b >= BATCH) return;
    double t0 = 0, t1 = 0, t2 = 0;
    for (int c = 0; c < NBLK_PER_B; c++) {
        const double* p = partial + ((size_t)b * NBLK_PER_B + c) * 3;
        t0 += p[0]; t1 += p[1]; t2 += p[2];
    }
    mean[b * 3 + 0] = t0 / (double)NPTS;
    mean[b * 3 + 1] = t1 / (double)NPTS;
    mean[b * 3 + 2] = t2 / (double)NPTS;
}

__global__ __launch_bounds__(256) void k_max(const float* __restrict__ pts,
                                             const double* __restrict__ mean,
                                             unsigned long long* __restrict__ maxsq) {
    int blk = blockIdx.x;
    int b = blk >> 4, c = blk & 15;
    double mx = mean[b * 3], my = mean[b * 3 + 1], mz = mean[b * 3 + 2];
    const float4* base = (const float4*)(pts + ((size_t)b * NPTS + (size_t)c * CHUNK) * 6);
    double m = 0.0;
    for (int i = threadIdx.x; i < CHUNK / 2; i += 256) {
        float4 v0 = base[(size_t)i * 3];
        float4 v1 = base[(size_t)i * 3 + 1];
        float4 v2 = base[(size_t)i * 3 + 2];
        double dx = (double)v0.x - mx, dy = (double)v0.y - my, dz = (double)v0.z - mz;
        m = fmax(m, dx * dx + dy * dy + dz * dz);
        dx = (double)v1.z - mx; dy = (double)v1.w - my; dz = (double)v2.x - mz;
        m = fmax(m, dx * dx + dy * dy + dz * dz);
    }
    for (int off = 32; off; off >>= 1)
        m = fmax(m, __shfl_down(m, off));
    __shared__ double sh[4];
    int lane = threadIdx.x & 63, w = threadIdx.x >> 6;
    if (lane == 0) sh[w] = m;
    __syncthreads();
    if (threadIdx.x == 0) {
        double t = fmax(fmax(sh[0], sh[1]), fmax(sh[2], sh[3]));
        atomicMax(&maxsq[b], (unsigned long long)__double_as_longlong(t));
    }
}

// One block per (batch, chunk, part). Streams only its chunk (CPTS points),
// LDS-accumulates its qx-slab's cells, then flushes the LDS grid to the global
// accum with coalesced distinct-address atomics.
__global__ __launch_bounds__(1024, 8) void k_scatter_lds(const float* __restrict__ pts,
                                                         const double* __restrict__ mean,
                                                         const unsigned long long* __restrict__ maxsq,
                                                         float* __restrict__ accum) {
    __shared__ float acc[PCELLS][4];
    int blk = blockIdx.x;
    int b = blk >> 4;
    int ch = (blk >> 2) & 3;
    int p = blk & 3;                 // qx in [6p, 6p+6)
    for (int c = threadIdx.x; c < PCELLS * 4; c += 1024)
        ((float*)acc)[c] = 0.0f;
    __syncthreads();

    double mx = mean[b * 3], my = mean[b * 3 + 1], mz = mean[b * 3 + 2];
    double denom = 2.0 * sqrt(__longlong_as_double((long long)maxsq[b]));
    // slab x-range (guard-banded f32 prefilter; exact f64 path decides)
    double xlo = mx + denom * (((double)(6 * p) - 0.5) / 24.0 - 0.5);
    double xhi = mx + denom * (((double)(6 * p) + 5.5) / 24.0 - 0.5);
    float flo = (p == 0)         ? -3.0e38f : (float)(xlo - 1e-4);
    float fhi = (p == NPART - 1) ?  3.0e38f : (float)(xhi + 1e-4);

    const float4* base = (const float4*)(pts + ((size_t)b * NPTS + (size_t)ch * CPTS) * 6);

    auto point = [&](float x, float y, float z, float f1, float f2, float f3) {
        if (x >= flo && x <= fhi) {
            double vx = ((double)x - mx) / denom + 0.5;
            vx = fmin(fmax(vx * 24.0, 0.0), 23.0);
            int qx = (int)rint(vx);
            if (qx >= 6 * p && qx < 6 * p + 6) {
                double vy = ((double)y - my) / denom + 0.5;
                double vz = ((double)z - mz) / denom + 0.5;
                vy = fmin(fmax(vy * 24.0, 0.0), 23.0);
                vz = fmin(fmax(vz * 24.0, 0.0), 23.0);
                int qy = (int)rint(vy);
                int qz = (int)rint(vz);
                int l = (qx - 6 * p) * (RES * RES) + qy * RES + qz;
                atomicAdd(&acc[l][0], 1.0f);
                atomicAdd(&acc[l][1], f1);
                atomicAdd(&acc[l][2], f2);
                atomicAdd(&acc[l][3], f3);
            }
        }
    };

    // CPTS/2 = 16384 point-pairs; 2 pairs (4 points, 6 float4) per thread-iter
    for (int it = 0; it < 8; ++it) {
        int pairA = it * 2048 + threadIdx.x;
        int pairB = pairA + 1024;
        float4 a0 = base[(size_t)pairA * 3];
        float4 a1 = base[(size_t)pairA * 3 + 1];
        float4 a2 = base[(size_t)pairA * 3 + 2];
        float4 b0 = base[(size_t)pairB * 3];
        float4 b1 = base[(size_t)pairB * 3 + 1];
        float4 b2 = base[(size_t)pairB * 3 + 2];
        point(a0.x, a0.y, a0.z, a0.w, a1.x, a1.y);
        point(a1.z, a1.w, a2.x, a2.y, a2.z, a2.w);
        point(b0.x, b0.y, b0.z, b0.w, b1.x, b1.y);
        point(b1.z, b1.w, b2.x, b2.y, b2.z, b2.w);
    }
    __syncthreads();

    // flush LDS grid to global accum (coalesced, distinct addresses; skip zeros)
    float* gacc = accum + ((size_t)b * R3 + (size_t)p * PCELLS) * 4;
    for (int c = threadIdx.x; c < PCELLS * 4; c += 1024) {
        float v = ((float*)acc)[c];
        if (v != 0.0f) atomicAdd(&gacc[c], v);
    }
}

__global__ __launch_bounds__(256) void k_final(const float* __restrict__ accum,
                                               float* __restrict__ out) {
    int cell = blockIdx.x * 256 + threadIdx.x;  // < BATCH*R3 (exact multiple)
    const float4 a = ((const float4*)accum)[cell];
    float cnt = a.x;
    int b = cell / R3;
    int r = cell - b * R3;
    size_t obase = (size_t)b * 4 * R3 + r;
    if (cnt > 0.0f) {
        out[obase]          = 1.0f;
        out[obase + R3]     = a.y / cnt;
        out[obase + 2 * R3] = a.z / cnt;
        out[obase + 3 * R3] = a.w / cnt;
    } else {
        out[obase]          = 0.0f;
        out[obase + R3]     = 0.0f;
        out[obase + 2 * R3] = 0.0f;
        out[obase + 3 * R3] = 0.0f;
    }
}

extern "C" void kernel_launch(void* const* d_in, const int* in_sizes, int n_in,
                              void* d_out, int out_size, void* d_ws, size_t ws_size,
                              hipStream_t stream) {
    const float* pts = (const float*)d_in[0];
    float* out = (float*)d_out;
    char* ws = (char*)d_ws;
    double* partial = (double*)(ws + WS_PARTIAL);
    double* mean = (double*)(ws + WS_MEAN);
    unsigned long long* maxsq = (unsigned long long*)(ws + WS_MAXSQ);
    float* accum = (float*)(ws + WS_ACCUM);

    hipMemsetAsync(ws + WS_MAXSQ, 0, (WS_ACCUM - WS_MAXSQ) + ACCUM_BYTES, stream);

    k_mean<<<BATCH * NBLK_PER_B, 256, 0, stream>>>(pts, partial);
    k_meanred<<<1, 64, 0, stream>>>(partial, mean);
    k_max<<<BATCH * NBLK_PER_B, 256, 0, stream>>>(pts, mean, maxsq);
    k_scatter_lds<<<BATCH * NCHUNK * NPART, 1024, 0, stream>>>(pts, mean, maxsq, accum);
    k_final<<<(BATCH * R3) / 256, 256, 0, stream>>>(accum, out);
}